// Round 1
// 1452.521 us; speedup vs baseline: 1.4332x; 1.4332x over previous
//
#include <hip/hip_runtime.h>

typedef float f32x2 __attribute__((ext_vector_type(2)));

constexpr int H=100, NIN=10, OUTN=10, NB=64, T=2048;
constexpr int RING=16, RM=RING-1, CHK=4;   // LDS rings 16 steps, 4-step chunks

#define PKF(acc,w,p) asm("v_pk_fma_f32 %0, %1, %2, %0":"+v"(acc):"v"(w),"v"(p))

// full 100-col dot for ONE row held in W[50] (f32x2 pairs), two acc chains
#define MV1(h4,a0,a1,W) \
  _Pragma("unroll") \
  for (int j_=0;j_<25;++j_){ \
    float4 hv_=(h4)[j_]; \
    f32x2 p0_; p0_.x=hv_.x; p0_.y=hv_.y; \
    f32x2 p1_; p1_.x=hv_.z; p1_.y=hv_.w; \
    PKF(a0,W[2*j_],p0_); PKF(a1,W[2*j_+1],p1_); }

// load one weight row (100 floats) into 50 f32x2 regs, masked
#define LDW1(W,base,rr,mk) \
  _Pragma("unroll") \
  for (int j_=0;j_<25;++j_){ \
    float4 w_=*(const float4*)((base)+(size_t)(rr)*H+4*j_); \
    W[2*j_].x=w_.x*(mk);   W[2*j_].y=w_.y*(mk); \
    W[2*j_+1].x=w_.z*(mk); W[2*j_+1].y=w_.w*(mk); }

__device__ __forceinline__ float ftanh(float x){
  float e=__expf(x+x); return 1.0f - 2.0f/(e+1.0f);
}

__device__ __forceinline__ void waitGE(int* f,int tgt){
  if (tgt<=0) return;
  while (__hip_atomic_load(f,__ATOMIC_RELAXED,__HIP_MEMORY_SCOPE_WORKGROUP)<tgt)
    __builtin_amdgcn_s_sleep(1);
  (void)__hip_atomic_load(f,__ATOMIC_ACQUIRE,__HIP_MEMORY_SCOPE_WORKGROUP);
}
__device__ __forceinline__ void pub(int* f,int v,int lane){
  if (lane==0) __hip_atomic_store(f,v,__ATOMIC_RELEASE,__HIP_MEMORY_SCOPE_WORKGROUP);
}
__device__ __forceinline__ void waitGEg(int* f,int tgt){
  if (tgt<=0) return;
  while (__hip_atomic_load(f,__ATOMIC_RELAXED,__HIP_MEMORY_SCOPE_AGENT)<tgt)
    __builtin_amdgcn_s_sleep(8);
  (void)__hip_atomic_load(f,__ATOMIC_ACQUIRE,__HIP_MEMORY_SCOPE_AGENT);
}
__device__ __forceinline__ void pubg(int* f,int v,int lane){
  if (lane==0) __hip_atomic_store(f,v,__ATOMIC_RELEASE,__HIP_MEMORY_SCOPE_AGENT);
}

// HH half: owns one row of Whh, recurrence h[t]=tanh(ihc[t]+Whh_row.h[t-1]).
// Per-step pair sync with the other row-half via sc counters.
__device__ __forceinline__ void hh_half(
    const int lane, const bool vr, const int rc,
    const f32x2 (&W)[50],
    float (*hrL)[H], const float (*icL)[H],
    int* scS, int* scP, int* fpi, int* fch1, int* fch2, int* fci,
    float* hfp)
{
  for (int m=0;m<T;m+=CHK){
    waitGE(fpi,m+CHK);                 // own-rows ihc ready
    waitGE(fch1,m-(RING-CHK));         // h-ring space (consumers)
    if (fch2) waitGE(fch2,m-(RING-CHK));
#pragma unroll
    for (int tt=0;tt<CHK;++tt){
      const int t=m+tt;
      waitGE(scP,t);                   // partner wrote its h rows of t-1
      const float4* h4=(const float4*)hrL[(t-1)&RM];
      const float ihv=icL[t&RM][rc];
      f32x2 a0,a1; a0.x=ihv; a0.y=0.f; a1.x=0.f; a1.y=0.f;
      MV1(h4,a0,a1,W)
      const float hn=ftanh(a0.x+a0.y+a1.x+a1.y);
      if (vr){
        hrL[t&RM][rc]=hn;
        if (t==T-1) hfp[rc]=hn;        // h_final
      }
      pub(scS,t+1,lane);               // h step t published
    }
    pub(fci,m+CHK,lane);               // consumed ihc chunk
  }
}

// IH half: ihc_row[t] = bias + Wih_row . h_src[t]; no recurrence -> chunked only
__device__ __forceinline__ void ih_half(
    const int lane, const bool vr, const int rc,
    const f32x2 (&W)[50], const float bs,
    const float (*hsrc)[H], const int srm,
    float (*icT)[H],
    int* f1, int* f2, int* fci, int* fchS, int* fpiS)
{
  for (int m=0;m<T;m+=CHK){
    waitGE(f1,m+CHK);                  // source h chunk ready
    if (f2) waitGE(f2,m+CHK);
    waitGE(fci,m-(RING-CHK));          // ic-ring space
#pragma unroll
    for (int tt=0;tt<CHK;++tt){
      const int t=m+tt;
      const float4* h4=(const float4*)hsrc[t&srm];
      f32x2 a0,a1; a0.x=bs; a0.y=0.f; a1.x=0.f; a1.y=0.f;
      MV1(h4,a0,a1,W)
      if (vr) icT[t&RM][rc]=a0.x+a0.y+a1.x+a1.y;
    }
    pub(fchS,m+CHK,lane);              // consumed source chunk
    pub(fpiS,m+CHK,lane);              // produced ihc chunk
  }
}

// grid 128 = 2 blocks/batch. bt0: layers 0-2 (11 waves); bt1: layers 3-4 + out.
// No __syncthreads in-loop; all pacing via LDS flags, one global h2 boundary.
__global__ __launch_bounds__(704)
__attribute__((amdgpu_waves_per_eu(3,4)))
void rnn5(const float* __restrict__ xg, const float* __restrict__ hprev,
          const float* __restrict__ Wih0, const float* __restrict__ Wih,
          const float* __restrict__ Whh, const float* __restrict__ bih,
          const float* __restrict__ bhh, const float* __restrict__ Wout,
          const float* __restrict__ bout, float* __restrict__ outf,
          float* __restrict__ h2g, int* __restrict__ gflags, int gring)
{
  __shared__ __align__(16) float hr[3][RING][H];   // h rings (3 local layers)
  __shared__ __align__(16) float ic[3][RING][H];   // ihc rings
  __shared__ __align__(16) float h2s[32][H];       // staged h2 (block B)
  __shared__ int flg[32];

  const int tid=threadIdx.x, wv=tid>>6, lane=tid&63;
  const int bt=blockIdx.x>>6, b=blockIdx.x&63;
  const size_t hfB=(size_t)NB*T*OUTN;
  const int Lbase=bt?3:0, NLOC=bt?2:3;

  if (tid<32) flg[tid]=0;
  for (int i=tid;i<NLOC*H;i+=704){
    const int li=i/H, r=i-li*H;
    hr[li][RM][r]=hprev[((size_t)(Lbase+li)*NB+b)*H+r];
  }
  __syncthreads();                                  // the ONLY barrier

  int* gp2=&gflags[b*16+0];
  int* gc2=&gflags[b*16+1];
  float* h2base=h2g+(size_t)b*gring*H;
  const int gm1=gring-1;

  if (bt==0){
    // flags A: 0-5 sc(hh l,half) | 6 pi0 | 7-10 pi1a,b,pi2a,b | 11-16 ci0a..ci2b
    //          17,18 ch0(by IH1a/b) | 19,20 ch1(by IH2a/b) | 21 ch2(copier)
    // waves: w0 HH1a w1 HH1b w2 HH2a w3 HH0a w4 IH1a w5 IH1b
    //        w6 HH2b w7 HH0b w8 IH2a w9 IH2b w10 IH0+h2copy   (SIMD-balanced)
    if (wv<4 || wv==6 || wv==7){
      int hl, half;
      if (wv==3){hl=0;half=0;} else if (wv==7){hl=0;half=1;}
      else if (wv==0){hl=1;half=0;} else if (wv==1){hl=1;half=1;}
      else if (wv==2){hl=2;half=0;} else {hl=2;half=1;}
      const int r=half*64+lane; const bool vr=r<H; const int rc=vr?r:96;
      const float mk=vr?1.f:0.f;
      f32x2 W[50]; LDW1(W,Whh+(size_t)hl*H*H,rc,mk)
      int* scS=&flg[2*hl+half]; int* scP=&flg[2*hl+(half^1)];
      int *fpi,*fch1,*fch2=nullptr,*fci;
      if (hl==0){ fpi=&flg[6];      fch1=&flg[17]; fch2=&flg[18]; fci=&flg[11+half]; }
      else if (hl==1){ fpi=&flg[7+half]; fch1=&flg[19]; fch2=&flg[20]; fci=&flg[13+half]; }
      else          { fpi=&flg[9+half]; fch1=&flg[21];               fci=&flg[15+half]; }
      hh_half(lane,vr,rc,W,hr[hl],(const float(*)[H])ic[hl],
              scS,scP,fpi,fch1,fch2,fci,
              outf+hfB+((size_t)hl*NB+b)*H);
    } else if (wv==4||wv==5||wv==8||wv==9){
      const int tl=(wv<6)?1:2, half=wv&1;
      const int r=half*64+lane; const bool vr=r<H; const int rc=vr?r:96;
      const float mk=vr?1.f:0.f;
      f32x2 W[50]; LDW1(W,Wih+(size_t)(tl-1)*H*H,rc,mk)
      const float bs=bih[(size_t)tl*H+rc]+bhh[(size_t)tl*H+rc];
      int* f1=&flg[2*(tl-1)]; int* f2=&flg[2*(tl-1)+1];
      int* fci =&flg[(tl==1?13:15)+half];
      int* fchS=&flg[(tl==1?17:19)+half];
      int* fpiS=&flg[(tl==1?7:9)+half];
      ih_half(lane,vr,rc,W,bs,(const float(*)[H])hr[tl-1],RM,ic[tl],
              f1,f2,fci,fchS,fpiS);
    } else {
      // ---- IH0 (x->ihc0) + h2 copier (hr[2] -> global ring), light wave ----
      const int r0=2*lane, r1=r0+1; const bool vr=r0<H;
      const int rc0=vr?r0:96, rc1=vr?r1:97; const float mk=vr?1.f:0.f;
      f32x2 XA[5],XB[5];
#pragma unroll
      for (int k=0;k<5;++k){
        f32x2 wa=*(const f32x2*)(Wih0+(size_t)rc0*NIN+2*k);
        f32x2 wb=*(const f32x2*)(Wih0+(size_t)rc1*NIN+2*k);
        XA[k].x=wa.x*mk; XA[k].y=wa.y*mk;
        XB[k].x=wb.x*mk; XB[k].y=wb.y*mk;
      }
      f32x2 bs; bs.x=bih[rc0]+bhh[rc0]; bs.y=bih[rc1]+bhh[rc1];
      const float* xb=xg+(size_t)b*T*NIN;
      f32x2 xc[CHK][5], xn[CHK][5];
#pragma unroll
      for (int tt=0;tt<CHK;++tt)
#pragma unroll
        for (int k=0;k<5;++k) xc[tt][k]=*(const f32x2*)(xb+(size_t)tt*NIN+2*k);
      for (int m=0;m<T;m+=CHK){
        waitGE(&flg[11],m-(RING-CHK));
        waitGE(&flg[12],m-(RING-CHK));
        if (m+CHK<T){
#pragma unroll
          for (int tt=0;tt<CHK;++tt)
#pragma unroll
            for (int k=0;k<5;++k)
              xn[tt][k]=*(const f32x2*)(xb+(size_t)(m+CHK+tt)*NIN+2*k);
        }
#pragma unroll
        for (int tt=0;tt<CHK;++tt){
          const int t=m+tt;
          f32x2 a0,a1; a0.x=bs.x;a0.y=0.f; a1.x=bs.y;a1.y=0.f;
#pragma unroll
          for (int k=0;k<5;++k){ PKF(a0,XA[k],xc[tt][k]); PKF(a1,XB[k],xc[tt][k]); }
          if (vr){
            f32x2 st; st.x=a0.x+a0.y; st.y=a1.x+a1.y;
            *(f32x2*)&ic[0][t&RM][r0]=st;
          }
        }
#pragma unroll
        for (int tt=0;tt<CHK;++tt)
#pragma unroll
          for (int k=0;k<5;++k) xc[tt][k]=xn[tt][k];
        pub(&flg[6],m+CHK,lane);                 // pi0 BEFORE copy-wait
        if (m>=16){                              // copy chunk m-16 (lag D=16)
          const int mc=m-16;
          waitGE(&flg[4],mc+CHK); waitGE(&flg[5],mc+CHK);   // sc2a/b
          waitGEg(gc2,mc+CHK-gring);                         // global ring space
          for (int q=0;q<4;++q){
            const int i=q*64+lane;
            if (i<200){
              const int sl=i/50, rr=2*(i-sl*50);
              f32x2 v=*(const f32x2*)&hr[2][(mc+sl)&RM][rr];
              *(f32x2*)&h2base[(size_t)((mc+sl)&gm1)*H+rr]=v;
            }
          }
          pub(&flg[21],mc+CHK,lane);                         // ch2copy
          if (((mc+CHK)&15)==0) pubg(gp2,mc+CHK,lane);       // 16-step global pub
        }
      }
      for (int mc=T-16;mc<T;mc+=CHK){            // tail: last 4 chunks
        waitGE(&flg[4],mc+CHK); waitGE(&flg[5],mc+CHK);
        waitGEg(gc2,mc+CHK-gring);
        for (int q=0;q<4;++q){
          const int i=q*64+lane;
          if (i<200){
            const int sl=i/50, rr=2*(i-sl*50);
            f32x2 v=*(const f32x2*)&hr[2][(mc+sl)&RM][rr];
            *(f32x2*)&h2base[(size_t)((mc+sl)&gm1)*H+rr]=v;
          }
        }
        pub(&flg[21],mc+CHK,lane);
        if (((mc+CHK)&15)==0) pubg(gp2,mc+CHK,lane);         // last = T
      }
    }
  } else {
    // flags B: 0-3 sc3a,b,sc4a,b | 4-7 pi3a,b,pi4a,b | 8-11 ci3a..ci4b
    //          12,13 ch3(by IH4a/b) | 14 ch4(by OUT) | 15 ph2s | 16,17 ch2sA/B
    // waves: w0 HH4a w1 HH4b w2 HH3a w3 HH3b w4 IH3a w5 IH3b
    //        w6 OUT  w7 STG  w8 IH4a w9 IH4b w10 idle
    if (wv<4){
      const int li=(wv<2)?1:0, half=wv&1, gl=3+li;
      const int r=half*64+lane; const bool vr=r<H; const int rc=vr?r:96;
      const float mk=vr?1.f:0.f;
      f32x2 W[50]; LDW1(W,Whh+(size_t)gl*H*H,rc,mk)
      int* scS=&flg[2*li+half]; int* scP=&flg[2*li+(half^1)];
      int *fpi=&flg[4+2*li+half], *fch1, *fch2=nullptr, *fci=&flg[8+2*li+half];
      if (li==0){ fch1=&flg[12]; fch2=&flg[13]; }
      else      { fch1=&flg[14]; }
      hh_half(lane,vr,rc,W,hr[li],(const float(*)[H])ic[li],
              scS,scP,fpi,fch1,fch2,fci,
              outf+hfB+((size_t)gl*NB+b)*H);
    } else if (wv==4||wv==5||wv==8||wv==9){
      const int li=(wv<6)?0:1, half=wv&1, gl=3+li;
      const int r=half*64+lane; const bool vr=r<H; const int rc=vr?r:96;
      const float mk=vr?1.f:0.f;
      f32x2 W[50]; LDW1(W,Wih+(size_t)(gl-1)*H*H,rc,mk)
      const float bs=bih[(size_t)gl*H+rc]+bhh[(size_t)gl*H+rc];
      int *f1,*f2=nullptr,*fci=&flg[8+2*li+half],*fchS,*fpiS=&flg[4+2*li+half];
      const float (*src)[H]; int srm;
      if (li==0){ src=(const float(*)[H])h2s;   srm=31; f1=&flg[15];
                  fchS=&flg[16+half]; }
      else      { src=(const float(*)[H])hr[0]; srm=RM; f1=&flg[0]; f2=&flg[1];
                  fchS=&flg[12+half]; }
      ih_half(lane,vr,rc,W,bs,src,srm,ic[li],f1,f2,fci,fchS,fpiS);
    } else if (wv==6){
      // ---- OUT: y = Wout.h4 + bout, lanes 0-9 own one row each ----
      const bool vr=lane<OUTN; const int rc=vr?lane:0; const float mk=vr?1.f:0.f;
      f32x2 W[50]; LDW1(W,Wout,rc,mk)
      const float bo=vr?bout[lane]:0.f;
      for (int m=0;m<T;m+=CHK){
        waitGE(&flg[2],m+CHK); waitGE(&flg[3],m+CHK);  // sc4a/b
#pragma unroll
        for (int tt=0;tt<CHK;++tt){
          const int t=m+tt;
          const float4* h4=(const float4*)hr[1][t&RM];
          f32x2 a0,a1; a0.x=bo;a0.y=0.f; a1.x=0.f;a1.y=0.f;
          MV1(h4,a0,a1,W)
          if (vr) outf[((size_t)b*T+t)*OUTN+lane]=a0.x+a0.y+a1.x+a1.y;
        }
        pub(&flg[14],m+CHK,lane);
      }
    } else if (wv==7){
      // ---- STG: global h2 ring -> h2s LDS (16-step chunks) ----
      for (int mc=0;mc<T;mc+=16){
        waitGEg(gp2,mc+16);
        waitGE(&flg[16],mc-16);
        waitGE(&flg[17],mc-16);
        for (int q=0;q<13;++q){
          const int i=q*64+lane;
          if (i<800){
            const int sl=i/50, rr=2*(i-sl*50);
            f32x2 v=*(const f32x2*)&h2base[(size_t)((mc+sl)&gm1)*H+rr];
            *(f32x2*)&h2s[(mc+sl)&31][rr]=v;
          }
        }
        pub(&flg[15],mc+16,lane);
        pubg(gc2,mc+16,lane);
      }
    }
    // wv==10: idle wave (keeps both block shapes at 704 threads)
  }
}

extern "C" void kernel_launch(void* const* d_in, const int* in_sizes, int n_in,
                              void* d_out, int out_size, void* d_ws, size_t ws_size,
                              hipStream_t stream){
  int* gflags=(int*)d_ws;                    // 64 batches x 2 flags, poison<0 ok
  float* h2g=(float*)((char*)d_ws+4096);
  int gring=128;
  while (gring>32 && 4096+(size_t)NB*gring*H*sizeof(float) > ws_size) gring>>=1;
  rnn5<<<dim3(128), dim3(704), 0, stream>>>(
    (const float*)d_in[0], (const float*)d_in[1], (const float*)d_in[2],
    (const float*)d_in[3], (const float*)d_in[4], (const float*)d_in[5],
    (const float*)d_in[6], (const float*)d_in[7], (const float*)d_in[8],
    (float*)d_out, h2g, gflags, gring);
}

// Round 3
// 1139.425 us; speedup vs baseline: 1.8270x; 1.2748x over previous
//
#include <hip/hip_runtime.h>

typedef float f32x2 __attribute__((ext_vector_type(2)));

constexpr int H=100, NIN=10, OUTN=10, NB=64, T=2048;
constexpr int RING=32, RM=RING-1, CHK=8, LAGC=48;

#define PKF(acc,w,p) asm("v_pk_fma_f32 %0, %1, %2, %0":"+v"(acc):"v"(w),"v"(p))

// load one weight row (100 floats) into 50 f32x2 regs, masked
#define LDW1(W,base,rr,mk) \
  _Pragma("unroll") \
  for (int j_=0;j_<25;++j_){ \
    float4 w_=*(const float4*)((base)+(size_t)(rr)*H+4*j_); \
    W[2*j_].x=w_.x*(mk);   W[2*j_].y=w_.y*(mk); \
    W[2*j_+1].x=w_.z*(mk); W[2*j_+1].y=w_.w*(mk); }

__device__ __forceinline__ float ftanh(float x){
  float e=__expf(x+x); return 1.0f - 2.0f/(e+1.0f);
}

__device__ __forceinline__ void waitGE(int* f,int tgt){
  if (tgt<=0) return;
  while (__hip_atomic_load(f,__ATOMIC_RELAXED,__HIP_MEMORY_SCOPE_WORKGROUP)<tgt)
    __builtin_amdgcn_s_sleep(1);
  (void)__hip_atomic_load(f,__ATOMIC_ACQUIRE,__HIP_MEMORY_SCOPE_WORKGROUP);
}
__device__ __forceinline__ void pub(int* f,int v,int lane){
  if (lane==0) __hip_atomic_store(f,v,__ATOMIC_RELEASE,__HIP_MEMORY_SCOPE_WORKGROUP);
}
__device__ __forceinline__ void waitGEg(int* f,int tgt){
  if (tgt<=0) return;
  while (__hip_atomic_load(f,__ATOMIC_RELAXED,__HIP_MEMORY_SCOPE_AGENT)<tgt)
    __builtin_amdgcn_s_sleep(8);
  (void)__hip_atomic_load(f,__ATOMIC_ACQUIRE,__HIP_MEMORY_SCOPE_AGENT);
}
__device__ __forceinline__ void pubg(int* f,int v,int lane){
  if (lane==0) __hip_atomic_store(f,v,__ATOMIC_RELEASE,__HIP_MEMORY_SCOPE_AGENT);
}

// Single-wave HH layer: lane i (<50) owns rows 2i,2i+1 (200 weight VGPRs).
// Recurrence fully wave-private; inter-wave flags only at CHK granularity.
// Fences every 4 j's keep <=4 float4 h-loads in flight (VGPR budget).
__device__ __forceinline__ void hh_wave(
    const int lane, const bool vr, const int cc,
    const f32x2 (&WA)[50], const f32x2 (&WB)[50],
    float (*hrL)[H], const float (*icL)[H],
    int* fpi1, int* fpi2, int* fch1, int* fch2,
    int* fph, int* fci, float* hfp)
{
  for (int m=0;m<T;m+=CHK){
    waitGE(fpi1,m+CHK); if (fpi2) waitGE(fpi2,m+CHK);
    waitGE(fch1,m-(RING-CHK)); if (fch2) waitGE(fch2,m-(RING-CHK));
#pragma unroll
    for (int tt=0;tt<CHK;++tt){
      const int t=m+tt;
      const float4* h4=(const float4*)hrL[(t-1)&RM];
      const f32x2 ih=*(const f32x2*)&icL[t&RM][cc];
      f32x2 aA0,aA1,aB0,aB1;
      aA0.x=ih.x; aA0.y=0.f; aA1.x=0.f; aA1.y=0.f;
      aB0.x=ih.y; aB0.y=0.f; aB1.x=0.f; aB1.y=0.f;
#pragma unroll
      for (int j=0;j<25;++j){
        float4 hv=h4[j];
        f32x2 p0; p0.x=hv.x; p0.y=hv.y;
        f32x2 p1; p1.x=hv.z; p1.y=hv.w;
        PKF(aA0,WA[2*j],p0); PKF(aA1,WA[2*j+1],p1);
        PKF(aB0,WB[2*j],p0); PKF(aB1,WB[2*j+1],p1);
        if ((j&3)==3) asm volatile("" ::: "memory");
      }
      const float hA=ftanh(aA0.x+aA0.y+aA1.x+aA1.y);
      const float hB=ftanh(aB0.x+aB0.y+aB1.x+aB1.y);
      if (vr){
        f32x2 st; st.x=hA; st.y=hB;
        *(f32x2*)&hrL[t&RM][cc]=st;
        if (t==T-1) *(f32x2*)&hfp[cc]=st;
      }
    }
    pub(fph,m+CHK,lane); pub(fci,m+CHK,lane);
  }
}

// Half-wave IH (one row/lane, 100 weight VGPRs): throughput stage.
__device__ __forceinline__ void ih_halfw(
    const int lane, const bool vr, const int rc,
    const f32x2 (&W)[50], const float bs,
    const float (*hsrc)[H], float (*icT)[H],
    int* fsrc, int* fspace, int* fchS, int* fpi)
{
  for (int m=0;m<T;m+=CHK){
    waitGE(fsrc,m+CHK);
    waitGE(fspace,m-(RING-CHK));
#pragma unroll
    for (int tt=0;tt<CHK;++tt){
      const int t=m+tt;
      const float4* h4=(const float4*)hsrc[t&RM];
      f32x2 a0,a1; a0.x=0.f;a0.y=0.f; a1=a0;
#pragma unroll
      for (int j=0;j<25;++j){
        float4 hv=h4[j];
        f32x2 p0; p0.x=hv.x; p0.y=hv.y;
        f32x2 p1; p1.x=hv.z; p1.y=hv.w;
        PKF(a0,W[2*j],p0); PKF(a1,W[2*j+1],p1);
        if ((j&3)==3) asm volatile("" ::: "memory");
      }
      if (vr) icT[t&RM][rc]=bs+a0.x+a0.y+a1.x+a1.y;
    }
    pub(fchS,m+CHK,lane); pub(fpi,m+CHK,lane);
  }
}

// Block A flags: 0 PH0 1 PH1 2 PH2 | 3 PI0 4 PI1A 5 PI1B 6 PI2A 7 PI2B
//                8 CI0 9 CI1 10 CI2 | 11 CH0A 12 CH0B 13 CH1A 14 CH1B 15 CH2
// Block B flags: 0 PH3 1 PH4 | 2 PI3A 3 PI3B 4 PI4A 5 PI4B | 6 CI3 7 CI4
//                8 CH3A 9 CH3B 10 CH4 | 11 PH2S 12 CH2SA 13 CH2SB
__global__ __launch_bounds__(512,2)
void rnn5(const float* __restrict__ xg, const float* __restrict__ hprev,
          const float* __restrict__ Wih0, const float* __restrict__ Wih,
          const float* __restrict__ Whh, const float* __restrict__ bih,
          const float* __restrict__ bhh, const float* __restrict__ Wout,
          const float* __restrict__ bout, float* __restrict__ outf,
          float* __restrict__ h2g, int* __restrict__ gflags, int gring)
{
  __shared__ __align__(16) float hr[3][RING][H];   // h rings
  __shared__ __align__(16) float ic[3][RING][H];   // ihc rings
  __shared__ __align__(16) float h2s[RING][H];     // staged h2 (block B)
  __shared__ int flg[16];

  const int tid=threadIdx.x, wv=tid>>6, lane=tid&63;
  const int bt=blockIdx.x>>6, b=blockIdx.x&63;
  const size_t hfB=(size_t)NB*T*OUTN;
  const int Lbase=bt?3:0, NLOC=bt?2:3;

  if (tid<16) flg[tid]=0;
  for (int i=tid;i<NLOC*H;i+=512){
    const int li=i/H, r=i-li*H;
    hr[li][RM][r]=hprev[((size_t)(Lbase+li)*NB+b)*H+r];
  }
  __syncthreads();                                  // the ONLY barrier

  int* gp2=&gflags[b*16+0];
  int* gc2=&gflags[b*16+1];
  float* h2base=h2g+(size_t)b*gring*H;
  const int gm1=gring-1;

  const bool vr2=(lane<50);
  const int cc=vr2?2*lane:96;
  const int rc0=vr2?2*lane:96, rc1=vr2?2*lane+1:97;
  const float mk2=vr2?1.f:0.f;

  if (bt==0){
    // waves: w0 HH0 w1 HH1 w2 HH2 w3 IH1a | w4 IH1b w5 IH2a w6 IH2b w7 IH0+cop
    // SIMD pairs: (HH0,IH1b)(HH1,IH2a)(HH2,IH2b)(IH1a,IH0+cop)
    if (wv<3){
      const int hl=wv;
      f32x2 WA[50],WB[50];
      LDW1(WA,Whh+(size_t)hl*H*H,rc0,mk2)
      LDW1(WB,Whh+(size_t)hl*H*H,rc1,mk2)
      int *fpi1,*fpi2=nullptr,*fch1,*fch2=nullptr;
      if (hl==0){ fpi1=&flg[3]; fch1=&flg[11]; fch2=&flg[12]; }
      else if (hl==1){ fpi1=&flg[4]; fpi2=&flg[5]; fch1=&flg[13]; fch2=&flg[14]; }
      else { fpi1=&flg[6]; fpi2=&flg[7]; fch1=&flg[15]; }
      hh_wave(lane,vr2,cc,WA,WB,hr[hl],(const float(*)[H])ic[hl],
              fpi1,fpi2,fch1,fch2,&flg[hl],&flg[8+hl],
              outf+hfB+((size_t)hl*NB+b)*H);
    } else if (wv!=7){
      // IH halves: w3 IH1a w4 IH1b (ic1 = Wih[0].h0) ; w5 IH2a w6 IH2b
      const int tl=(wv<=4)?1:2, half=(wv==4||wv==6)?1:0;
      const int r=half*64+lane;
      const bool vr=r<H; const int rc=vr?r:96; const float mk=vr?1.f:0.f;
      f32x2 W[50]; LDW1(W,Wih+(size_t)(tl-1)*H*H,rc,mk)
      const float bs=bih[(size_t)tl*H+rc]+bhh[(size_t)tl*H+rc];
      ih_halfw(lane,vr,rc,W,bs,(const float(*)[H])hr[tl-1],ic[tl],
               &flg[tl-1],&flg[8+tl],&flg[11+2*(tl-1)+half],&flg[4+2*(tl-1)+half]);
    } else {
      // ---- IH0 (x->ic0, 2 rows/lane, tiny K=10) + h2 copier ----
      f32x2 XA[5],XB[5];
#pragma unroll
      for (int k=0;k<5;++k){
        f32x2 wa=*(const f32x2*)(Wih0+(size_t)rc0*NIN+2*k);
        f32x2 wb=*(const f32x2*)(Wih0+(size_t)rc1*NIN+2*k);
        XA[k].x=wa.x*mk2; XA[k].y=wa.y*mk2;
        XB[k].x=wb.x*mk2; XB[k].y=wb.y*mk2;
      }
      f32x2 bs; bs.x=bih[rc0]+bhh[rc0]; bs.y=bih[rc1]+bhh[rc1];
      const f32x2* xb2=(const f32x2*)(xg+(size_t)b*T*NIN);

      auto copy8=[&](int mc){
        waitGE(&flg[2],mc+CHK);                 // PH2 chunk ready
        waitGEg(gc2,mc+CHK-gring);              // global ring space
#pragma unroll
        for (int q=0;q<7;++q){
          const int i=q*64+lane;
          if (i<CHK*50){
            const int sl=i/50, rr=2*(i-sl*50);
            f32x2 v=*(const f32x2*)&hr[2][(mc+sl)&RM][rr];
            *(f32x2*)&h2base[(size_t)((mc+sl)&gm1)*H+rr]=v;
          }
        }
        pub(&flg[15],mc+CHK,lane);              // CH2
        if (((mc+CHK)&15)==0) pubg(gp2,mc+CHK,lane);
      };

      for (int m=0;m<T;m+=CHK){
        waitGE(&flg[8],m-(RING-CHK));           // CI0 space
#pragma unroll
        for (int tt=0;tt<CHK;++tt){
          f32x2 xv[5];
#pragma unroll
          for (int k=0;k<5;++k) xv[k]=xb2[(size_t)(m+tt)*5+k];
          f32x2 a0,a1; a0.x=bs.x;a0.y=0.f; a1.x=bs.y;a1.y=0.f;
#pragma unroll
          for (int k=0;k<5;++k){ PKF(a0,XA[k],xv[k]); PKF(a1,XB[k],xv[k]); }
          if (vr2){
            f32x2 st; st.x=a0.x+a0.y; st.y=a1.x+a1.y;
            *(f32x2*)&ic[0][(m+tt)&RM][cc]=st;
          }
        }
        pub(&flg[3],m+CHK,lane);                // PI0 (before copy-wait!)
        if (m>=LAGC) copy8(m-LAGC);
      }
      for (int mc=T-LAGC;mc<T;mc+=CHK) copy8(mc);
    }
  } else {
    // waves: w0 HH3 w1 HH4 w2 IH3a w3 IH4a | w4 OUT w5 STG w6 IH3b w7 IH4b
    // SIMD pairs: (HH3,OUT)(HH4,STG)(IH3a,IH3b)(IH4a,IH4b)
    if (wv<2){
      const int li=wv, gl=3+li;
      f32x2 WA[50],WB[50];
      LDW1(WA,Whh+(size_t)gl*H*H,rc0,mk2)
      LDW1(WB,Whh+(size_t)gl*H*H,rc1,mk2)
      int *fpi1,*fpi2,*fch1,*fch2=nullptr;
      if (li==0){ fpi1=&flg[2]; fpi2=&flg[3]; fch1=&flg[8]; fch2=&flg[9]; }
      else      { fpi1=&flg[4]; fpi2=&flg[5]; fch1=&flg[10]; }
      hh_wave(lane,vr2,cc,WA,WB,hr[li],(const float(*)[H])ic[li],
              fpi1,fpi2,fch1,fch2,&flg[li],&flg[6+li],
              outf+hfB+((size_t)gl*NB+b)*H);
    } else if (wv==2||wv==3||wv==6||wv==7){
      // IH3 (src h2s -> ic0), IH4 (src hr0=h3 -> ic1), split in halves
      const int li=(wv==2||wv==6)?0:1, half=(wv>=6)?1:0, gl=3+li;
      const int r=half*64+lane;
      const bool vr=r<H; const int rc=vr?r:96; const float mk=vr?1.f:0.f;
      f32x2 W[50]; LDW1(W,Wih+(size_t)(gl-1)*H*H,rc,mk)
      const float bs=bih[(size_t)gl*H+rc]+bhh[(size_t)gl*H+rc];
      const float (*src)[H]=(li==0)?(const float(*)[H])h2s
                                   :(const float(*)[H])hr[0];
      int* fsrc=(li==0)?&flg[11]:&flg[0];
      int* fchS=(li==0)?&flg[12+half]:&flg[8+half];
      ih_halfw(lane,vr,rc,W,bs,src,ic[li],
               fsrc,&flg[6+li],fchS,&flg[2+2*li+half]);
    } else if (wv==4){
      // ---- OUT: y = Wout.h4 + bout (lanes 0-9 own one row) ----
      const bool vr=lane<OUTN; const int rc=vr?lane:0; const float mk=vr?1.f:0.f;
      f32x2 W[50]; LDW1(W,Wout,rc,mk)
      const float bo=vr?bout[lane]:0.f;
      const size_t yB=(size_t)b*T*OUTN;
      for (int m=0;m<T;m+=CHK){
        waitGE(&flg[1],m+CHK);                  // PH4
#pragma unroll
        for (int tt=0;tt<CHK;++tt){
          const int t=m+tt;
          const float4* h4=(const float4*)hr[1][t&RM];
          f32x2 a0,a1; a0.x=bo;a0.y=0.f; a1.x=0.f;a1.y=0.f;
#pragma unroll
          for (int j=0;j<25;++j){
            float4 hv=h4[j];
            f32x2 p0; p0.x=hv.x; p0.y=hv.y;
            f32x2 p1; p1.x=hv.z; p1.y=hv.w;
            PKF(a0,W[2*j],p0); PKF(a1,W[2*j+1],p1);
            if ((j&3)==3) asm volatile("" ::: "memory");
          }
          if (vr) outf[yB+(size_t)t*OUTN+lane]=a0.x+a0.y+a1.x+a1.y;
        }
        pub(&flg[10],m+CHK,lane);               // CH4
      }
    } else {
      // ---- STG: global h2 ring -> h2s (16-step chunks) ----
      for (int mc=0;mc<T;mc+=16){
        waitGEg(gp2,mc+16);
        waitGE(&flg[12],mc-16);                 // CH2SA space
        waitGE(&flg[13],mc-16);                 // CH2SB space
        for (int q=0;q<13;++q){
          const int i=q*64+lane;
          if (i<800){
            const int sl=i/50, rr=2*(i-sl*50);
            f32x2 v=*(const f32x2*)&h2base[(size_t)((mc+sl)&gm1)*H+rr];
            *(f32x2*)&h2s[(mc+sl)&RM][rr]=v;
          }
        }
        pub(&flg[11],mc+16,lane);               // PH2S
        pubg(gc2,mc+16,lane);
      }
    }
  }
}

extern "C" void kernel_launch(void* const* d_in, const int* in_sizes, int n_in,
                              void* d_out, int out_size, void* d_ws, size_t ws_size,
                              hipStream_t stream){
  int* gflags=(int*)d_ws;                    // 64 batches x 2 flags (poison<0 ok)
  float* h2g=(float*)((char*)d_ws+4096);
  int gring=128;
  while (gring>32 && 4096+(size_t)NB*gring*H*sizeof(float) > ws_size) gring>>=1;
  rnn5<<<dim3(128), dim3(512), 0, stream>>>(
    (const float*)d_in[0], (const float*)d_in[1], (const float*)d_in[2],
    (const float*)d_in[3], (const float*)d_in[4], (const float*)d_in[5],
    (const float*)d_in[6], (const float*)d_in[7], (const float*)d_in[8],
    (float*)d_out, h2g, gflags, gring);
}